// Round 6
// baseline (381.442 us; speedup 1.0000x reference)
//
#include <hip/hip_runtime.h>
#include <stdint.h>

#define BATCH 2
#define SEQ   2048
#define DIM   1024
#define NH    16
#define DH    64

typedef short bf16x8 __attribute__((ext_vector_type(8)));
typedef float floatx4 __attribute__((ext_vector_type(4)));

__device__ __forceinline__ int swz(int r) { return (r ^ (r >> 2)) & 3; }

// Split two fp32 into packed bf16 hi-pair and lo-pair (truncation split)
__device__ __forceinline__ void split2(float x0, float x1, uint32_t& hi, uint32_t& lo) {
    uint32_t u0 = __float_as_uint(x0), u1 = __float_as_uint(x1);
    uint32_t m0 = u0 & 0xFFFF0000u;
    uint32_t m1 = u1 & 0xFFFF0000u;
    hi = (u0 >> 16) | m1;
    float l0 = x0 - __uint_as_float(m0);
    float l1 = x1 - __uint_as_float(m1);
    lo = (__float_as_uint(l0) >> 16) | (__float_as_uint(l1) & 0xFFFF0000u);
}

__device__ __forceinline__ uint32_t pack_bf16_rne(float x0, float x1) {
    uint32_t u0 = __float_as_uint(x0), u1 = __float_as_uint(x1);
    u0 += 0x7FFFu + ((u0 >> 16) & 1);
    u1 += 0x7FFFu + ((u1 >> 16) & 1);
    return (u0 >> 16) | (u1 & 0xFFFF0000u);
}

// async global->LDS, 16 B per lane. LDS dest = wave-uniform base + lane*16.
__device__ __forceinline__ void dma16(uint32_t* lds, const uint32_t* g) {
    __builtin_amdgcn_global_load_lds(
        (const __attribute__((address_space(1))) uint32_t*)g,
        (__attribute__((address_space(3))) uint32_t*)lds, 16, 0, 0);
}

// ---------------- input convert: fp32 [4096][1024] -> split h/l words -------
__global__ __launch_bounds__(256)
void convert_in(const float* __restrict__ qv_in, const float* __restrict__ k_in,
                uint32_t* __restrict__ aqh, uint32_t* __restrict__ aql,
                uint32_t* __restrict__ akh, uint32_t* __restrict__ akl)
{
    int bid = blockIdx.x;
    const float* src; uint32_t *dh, *dl;
    if (bid < 2048) { src = qv_in; dh = aqh; dl = aql; }
    else            { src = k_in;  dh = akh; dl = akl; bid -= 2048; }
    size_t fbase = (size_t)bid * 2048 + threadIdx.x * 8;
    float f[8];
    *(float4*)&f[0] = *(const float4*)&src[fbase];
    *(float4*)&f[4] = *(const float4*)&src[fbase + 4];
    uint32_t h[4], l[4];
    #pragma unroll
    for (int j = 0; j < 4; j++) split2(f[2 * j], f[2 * j + 1], h[j], l[j]);
    size_t wbase = fbase >> 1;
    *(uint4*)&dh[wbase] = make_uint4(h[0], h[1], h[2], h[3]);
    *(uint4*)&dl[wbase] = make_uint4(l[0], l[1], l[2], l[3]);
}

// ---------------- bf16x3 MFMA GEMM, 128 x TN tile ---------------------------
// A: pre-split bf16 [M][512 words], staged via swizzled-source global_load_lds
//    (source column = (kb ^ swz(row)); frag read at (quad ^ swz(row)) -> 2-way
//     bank aliasing only = free).
// B: fp32 [K][N], in-kernel split + transpose + swizzle (R2-R4-proven).
// EPI: 0 = fp32+bias -> Cf; 1 = qv (cols<1024 split -> O1h/O1l, else bf16 -> O2);
//      2 = split -> O1h/O1l.  M=4096, K=1024 fixed.
template<int TN, int EPI>
__global__ __launch_bounds__(256, 3)
void gemm_bt(const uint32_t* __restrict__ Ahg, const uint32_t* __restrict__ Alg,
             const float* __restrict__ Bf, const float* __restrict__ bias,
             float* __restrict__ Cf,
             uint32_t* __restrict__ O1h, uint32_t* __restrict__ O1l,
             uint32_t* __restrict__ O2, int N)
{
    constexpr int NF = TN / 32;              // n-frags per wave
    __shared__ uint32_t Ah[128 * 16], Al[128 * 16];
    __shared__ uint32_t Bh[TN * 16],  Bl[TN * 16];

    const int t    = threadIdx.x;
    const int lane = t & 63;
    const int w    = t >> 6;
    const int wm   = w & 1, wn = w >> 1;
    const int quad = lane >> 4, l15 = lane & 15;
    const int m0 = blockIdx.y * 128, n0 = blockIdx.x * TN;

    floatx4 acc[4][NF];
    #pragma unroll
    for (int i = 0; i < 4; i++)
        #pragma unroll
        for (int j = 0; j < NF; j++)
            #pragma unroll
            for (int e = 0; e < 4; e++) acc[i][j][e] = 0.0f;

    for (int k0 = 0; k0 < 1024; k0 += 32) {
        if (k0) __syncthreads();
        const int kw0 = k0 >> 1;
        // ---- stage A via DMA, swizzle in source address ----
        #pragma unroll
        for (int r = 0; r < 2; r++) {
            int block = r * 256 + w * 64 + lane;   // 512 blocks of 16 B per buffer
            int row = block >> 2;
            int kbl = lane & 3;                    // LDS kb slot
            size_t g = (size_t)(m0 + row) * 512 + kw0 + ((kbl ^ swz(row)) * 4);
            dma16(&Ah[block * 4], &Ahg[g]);
            dma16(&Al[block * 4], &Alg[g]);
        }
        // ---- stage B: fp32 -> split + transpose to [n][16w] swizzled ----
        if constexpr (TN == 128) {
            const int bc = (t & 31) * 4;
            const int bk = (t >> 5) * 4;
            const int bb = bk >> 3;
            const int bp = (bk & 7) >> 1;
            float4 g4[4];
            #pragma unroll
            for (int j = 0; j < 4; j++)
                g4[j] = *(const float4*)&Bf[(size_t)(k0 + bk + j) * N + n0 + bc];
            #pragma unroll
            for (int nn = 0; nn < 4; nn++) {
                int n = bc + nn;
                float e0 = ((const float*)&g4[0])[nn];
                float e1 = ((const float*)&g4[1])[nn];
                float e2 = ((const float*)&g4[2])[nn];
                float e3 = ((const float*)&g4[3])[nn];
                uint32_t h0, q0, h1, q1;
                split2(e0, e1, h0, q0);
                split2(e2, e3, h1, q1);
                int bi = n * 16 + ((bb ^ swz(n)) * 4) + bp;
                *(uint2*)&Bh[bi] = make_uint2(h0, h1);
                *(uint2*)&Bl[bi] = make_uint2(q0, q1);
            }
        } else {
            const int bc  = (t & 15) * 4;          // 16 col-groups x 4
            const int bk  = (t >> 4) * 2;          // 16 k-groups x 2
            const int bkw = bk >> 1;               // word column 0..15
            const int kb  = bkw >> 2, wo = bkw & 3;
            float4 g0 = *(const float4*)&Bf[(size_t)(k0 + bk) * N + n0 + bc];
            float4 g1 = *(const float4*)&Bf[(size_t)(k0 + bk + 1) * N + n0 + bc];
            const float* p0 = (const float*)&g0;
            const float* p1 = (const float*)&g1;
            #pragma unroll
            for (int nn = 0; nn < 4; nn++) {
                int n = bc + nn;
                uint32_t h, l;
                split2(p0[nn], p1[nn], h, l);
                int bi = n * 16 + ((kb ^ swz(n)) * 4) + wo;
                Bh[bi] = h;
                Bl[bi] = l;
            }
        }
        __syncthreads();

        // ---- fragments + swapped MFMA (lane l15 = C-row) ----
        bf16x8 vbh[NF], vbl[NF];
        #pragma unroll
        for (int fn = 0; fn < NF; fn++) {
            int br = wn * (TN / 2) + fn * 16 + l15;
            int bi = br * 16 + ((quad ^ swz(br)) * 4);
            vbh[fn] = *(const bf16x8*)&Bh[bi];
            vbl[fn] = *(const bf16x8*)&Bl[bi];
        }
        #pragma unroll
        for (int fm = 0; fm < 4; fm++) {
            int arow = wm * 64 + fm * 16 + l15;
            int ai = arow * 16 + ((quad ^ swz(arow)) * 4);
            bf16x8 vah = *(const bf16x8*)&Ah[ai];
            bf16x8 val = *(const bf16x8*)&Al[ai];
            #pragma unroll
            for (int fn = 0; fn < NF; fn++) {
                acc[fm][fn] = __builtin_amdgcn_mfma_f32_16x16x32_bf16(vbh[fn], vah, acc[fm][fn], 0, 0, 0);
                acc[fm][fn] = __builtin_amdgcn_mfma_f32_16x16x32_bf16(vbl[fn], vah, acc[fm][fn], 0, 0, 0);
                acc[fm][fn] = __builtin_amdgcn_mfma_f32_16x16x32_bf16(vbh[fn], val, acc[fm][fn], 0, 0, 0);
            }
        }
    }

    // ---- epilogue ----
    #pragma unroll
    for (int fm = 0; fm < 4; fm++) {
        int row = m0 + wm * 64 + fm * 16 + l15;
        #pragma unroll
        for (int fn = 0; fn < NF; fn++) {
            int colb = n0 + wn * (TN / 2) + fn * 16 + quad * 4;
            floatx4 a = acc[fm][fn];
            if (EPI == 0) {
                float4 bb4 = *(const float4*)&bias[colb];
                float4 v;
                v.x = a[0] + bb4.x; v.y = a[1] + bb4.y;
                v.z = a[2] + bb4.z; v.w = a[3] + bb4.w;
                *(float4*)&Cf[(size_t)row * N + colb] = v;
            } else if (EPI == 1) {
                if (colb < 1024) {
                    uint32_t h0, l0, h1, l1;
                    split2(a[0], a[1], h0, l0);
                    split2(a[2], a[3], h1, l1);
                    size_t wi = (size_t)row * 512 + (colb >> 1);
                    *(uint2*)&O1h[wi] = make_uint2(h0, h1);
                    *(uint2*)&O1l[wi] = make_uint2(l0, l1);
                } else {
                    uint32_t w0 = pack_bf16_rne(a[0], a[1]);
                    uint32_t w1 = pack_bf16_rne(a[2], a[3]);
                    *(uint2*)&O2[(size_t)row * 512 + ((colb - 1024) >> 1)] = make_uint2(w0, w1);
                }
            } else {
                uint32_t h0, l0, h1, l1;
                split2(a[0], a[1], h0, l0);
                split2(a[2], a[3], h1, l1);
                size_t wi = (size_t)row * 512 + (colb >> 1);
                *(uint2*)&O1h[wi] = make_uint2(h0, h1);
                *(uint2*)&O1l[wi] = make_uint2(l0, l1);
            }
        }
    }
}

// ---------------- MFMA flash attention, Br=128, Bc=64 -----------------------
// Q fragments held in registers (loaded once via transient staging through the
// K/V/P buffers -> no Qh/Ql arrays; LDS 43.5 KB -> 3 blocks/CU).
#define FST 34
__global__ __launch_bounds__(256, 3)
void flash_attn(const uint32_t* __restrict__ qhg, const uint32_t* __restrict__ qlg,
                const uint32_t* __restrict__ khg, const uint32_t* __restrict__ klg,
                const uint32_t* __restrict__ vbg,
                uint32_t* __restrict__ xhg, uint32_t* __restrict__ xlg)
{
    __shared__ uint32_t Kh[64 * FST], Kl[64 * FST];
    __shared__ uint32_t Vt[64 * FST];
    __shared__ uint32_t Pt[128 * FST];

    const int t    = threadIdx.x;
    const int lane = t & 63;
    const int w    = t >> 6;
    const int quad = lane >> 4, l15 = lane & 15;
    const int qb = blockIdx.x;
    const int h  = blockIdx.y;
    const int b  = blockIdx.z;
    const float scale = 0.125f;

    const size_t rowbase = (size_t)b * SEQ;

    // ---- stage Q transiently: rows 0..63 -> Kh(h)/Vt(l), 64..127 -> Kl(h)/Pt(l)
    {
        int row = t >> 1, c0 = (t & 1) * 16;
        uint32_t* dH = (row < 64) ? &Kh[row * FST] : &Kl[(row - 64) * FST];
        uint32_t* dL = (row < 64) ? &Vt[row * FST] : &Pt[(row - 64) * FST];
        size_t gw = (rowbase + qb * 128 + row) * 512 + h * 32 + c0;
        #pragma unroll
        for (int j = 0; j < 4; j++) {
            *(uint4*)&dH[c0 + j * 4] = *(const uint4*)&qhg[gw + j * 4];
            *(uint4*)&dL[c0 + j * 4] = *(const uint4*)&qlg[gw + j * 4];
        }
    }
    __syncthreads();

    // ---- preload this wave's Q fragments into registers ----
    bf16x8 vqh[2][2], vql[2][2];     // [nf][s]
    {
        const uint32_t* bH = (w < 2) ? Kh : Kl;
        const uint32_t* bL = (w < 2) ? Vt : Pt;
        #pragma unroll
        for (int nf = 0; nf < 2; nf++)
            #pragma unroll
            for (int s = 0; s < 2; s++) {
                int qr = (w & 1) * 32 + nf * 16 + l15;   // row within the 64-row half
                vqh[nf][s] = *(const bf16x8*)&bH[qr * FST + s * 16 + quad * 4];
                vql[nf][s] = *(const bf16x8*)&bL[qr * FST + s * 16 + quad * 4];
            }
    }

    float m_i[2] = {-INFINITY, -INFINITY};
    float l_i[2] = {0.0f, 0.0f};
    floatx4 acc_o[2][4];
    #pragma unroll
    for (int nf = 0; nf < 2; nf++)
        #pragma unroll
        for (int fm = 0; fm < 4; fm++)
            #pragma unroll
            for (int e = 0; e < 4; e++) acc_o[nf][fm][e] = 0.0f;

    for (int kt = 0; kt < SEQ / 64; kt++) {
        __syncthreads();   // first iter: Q-frag preload done; later: prev readers done
        // ---- stage K tile ----
        {
            int row = t >> 2, c0 = (t & 3) * 8;
            size_t gw = (rowbase + kt * 64 + row) * 512 + h * 32 + c0;
            *(uint4*)&Kh[row * FST + c0]     = *(const uint4*)&khg[gw];
            *(uint4*)&Kh[row * FST + c0 + 4] = *(const uint4*)&khg[gw + 4];
            *(uint4*)&Kl[row * FST + c0]     = *(const uint4*)&klg[gw];
            *(uint4*)&Kl[row * FST + c0 + 4] = *(const uint4*)&klg[gw + 4];
        }
        // ---- stage V transposed: Vt[d][key] ----
        {
            int key0 = (t & 15) * 4, d0 = (t >> 4) * 4;
            uint2 v0 = *(const uint2*)&vbg[(rowbase + kt * 64 + key0 + 0) * 512 + h * 32 + (d0 >> 1)];
            uint2 v1 = *(const uint2*)&vbg[(rowbase + kt * 64 + key0 + 1) * 512 + h * 32 + (d0 >> 1)];
            uint2 v2 = *(const uint2*)&vbg[(rowbase + kt * 64 + key0 + 2) * 512 + h * 32 + (d0 >> 1)];
            uint2 v3 = *(const uint2*)&vbg[(rowbase + kt * 64 + key0 + 3) * 512 + h * 32 + (d0 >> 1)];
            uint32_t lo, hi;
            lo = (v0.x & 0xFFFFu) | (v1.x << 16);
            hi = (v2.x & 0xFFFFu) | (v3.x << 16);
            *(uint2*)&Vt[(d0 + 0) * FST + (key0 >> 1)] = make_uint2(lo, hi);
            lo = (v0.x >> 16) | (v1.x & 0xFFFF0000u);
            hi = (v2.x >> 16) | (v3.x & 0xFFFF0000u);
            *(uint2*)&Vt[(d0 + 1) * FST + (key0 >> 1)] = make_uint2(lo, hi);
            lo = (v0.y & 0xFFFFu) | (v1.y << 16);
            hi = (v2.y & 0xFFFFu) | (v3.y << 16);
            *(uint2*)&Vt[(d0 + 2) * FST + (key0 >> 1)] = make_uint2(lo, hi);
            lo = (v0.y >> 16) | (v1.y & 0xFFFF0000u);
            hi = (v2.y >> 16) | (v3.y & 0xFFFF0000u);
            *(uint2*)&Vt[(d0 + 3) * FST + (key0 >> 1)] = make_uint2(lo, hi);
        }
        __syncthreads();

        // ---- S^T = K·Q^T (bf16x3), Q from registers ----
        floatx4 sacc[2][4];
        #pragma unroll
        for (int nf = 0; nf < 2; nf++)
            #pragma unroll
            for (int fm = 0; fm < 4; fm++)
                #pragma unroll
                for (int e = 0; e < 4; e++) sacc[nf][fm][e] = 0.0f;

        #pragma unroll
        for (int s = 0; s < 2; s++) {
            #pragma unroll
            for (int fm = 0; fm < 4; fm++) {
                int ki = (fm * 16 + l15) * FST + s * 16 + quad * 4;
                bf16x8 vkh = *(const bf16x8*)&Kh[ki];
                bf16x8 vkl = *(const bf16x8*)&Kl[ki];
                #pragma unroll
                for (int nf = 0; nf < 2; nf++) {
                    sacc[nf][fm] = __builtin_amdgcn_mfma_f32_16x16x32_bf16(vkh, vqh[nf][s], sacc[nf][fm], 0, 0, 0);
                    sacc[nf][fm] = __builtin_amdgcn_mfma_f32_16x16x32_bf16(vkh, vql[nf][s], sacc[nf][fm], 0, 0, 0);
                    sacc[nf][fm] = __builtin_amdgcn_mfma_f32_16x16x32_bf16(vkl, vqh[nf][s], sacc[nf][fm], 0, 0, 0);
                }
            }
        }

        // ---- online softmax per (lane, nf) ----
        #pragma unroll
        for (int nf = 0; nf < 2; nf++) {
            float p[4][4];
            float mt = -INFINITY;
            #pragma unroll
            for (int fm = 0; fm < 4; fm++)
                #pragma unroll
                for (int r = 0; r < 4; r++) {
                    p[fm][r] = sacc[nf][fm][r] * scale;
                    mt = fmaxf(mt, p[fm][r]);
                }
            mt = fmaxf(mt, __shfl_xor(mt, 16));
            mt = fmaxf(mt, __shfl_xor(mt, 32));
            float m_new = fmaxf(m_i[nf], mt);
            float alpha = __expf(m_i[nf] - m_new);
            float rs = 0.0f;
            #pragma unroll
            for (int fm = 0; fm < 4; fm++)
                #pragma unroll
                for (int r = 0; r < 4; r++) {
                    p[fm][r] = __expf(p[fm][r] - m_new);
                    rs += p[fm][r];
                }
            rs += __shfl_xor(rs, 16);
            rs += __shfl_xor(rs, 32);
            l_i[nf] = l_i[nf] * alpha + rs;
            m_i[nf] = m_new;
            #pragma unroll
            for (int fm = 0; fm < 4; fm++)
                #pragma unroll
                for (int e = 0; e < 4; e++) acc_o[nf][fm][e] *= alpha;

            int qrow = w * 32 + nf * 16 + l15;
            #pragma unroll
            for (int fm = 0; fm < 4; fm++) {
                uint32_t u0 = pack_bf16_rne(p[fm][0], p[fm][1]);
                uint32_t u1 = pack_bf16_rne(p[fm][2], p[fm][3]);
                *(uint2*)&Pt[qrow * FST + fm * 8 + quad * 2] = make_uint2(u0, u1);
            }
        }

        // ---- O^T += Vt · P^T ----
        #pragma unroll
        for (int s = 0; s < 2; s++) {
            bf16x8 pb[2];
            #pragma unroll
            for (int nf = 0; nf < 2; nf++)
                pb[nf] = *(const bf16x8*)&Pt[(w * 32 + nf * 16 + l15) * FST + s * 16 + quad * 4];
            #pragma unroll
            for (int fm = 0; fm < 4; fm++) {
                bf16x8 va = *(const bf16x8*)&Vt[(fm * 16 + l15) * FST + s * 16 + quad * 4];
                #pragma unroll
                for (int nf = 0; nf < 2; nf++)
                    acc_o[nf][fm] = __builtin_amdgcn_mfma_f32_16x16x32_bf16(va, pb[nf], acc_o[nf][fm], 0, 0, 0);
            }
        }
    }

    // ---- epilogue: write x pre-split bf16 ----
    #pragma unroll
    for (int nf = 0; nf < 2; nf++) {
        float rl = 1.0f / l_i[nf];
        size_t row = rowbase + qb * 128 + w * 32 + nf * 16 + l15;
        #pragma unroll
        for (int fm = 0; fm < 4; fm++) {
            int d0 = fm * 16 + quad * 4;
            uint32_t h0, l0, h1, l1;
            split2(acc_o[nf][fm][0] * rl, acc_o[nf][fm][1] * rl, h0, l0);
            split2(acc_o[nf][fm][2] * rl, acc_o[nf][fm][3] * rl, h1, l1);
            size_t wi = row * 512 + ((h * 64 + d0) >> 1);
            *(uint2*)&xhg[wi] = make_uint2(h0, h1);
            *(uint2*)&xlg[wi] = make_uint2(l0, l1);
        }
    }
}

extern "C" void kernel_launch(void* const* d_in, const int* in_sizes, int n_in,
                              void* d_out, int out_size, void* d_ws, size_t ws_size,
                              hipStream_t stream)
{
    const float* input_qv = (const float*)d_in[0];
    const float* input_k  = (const float*)d_in[1];
    const float* W_qv     = (const float*)d_in[2];
    const float* W_k      = (const float*)d_in[3];
    const float* W_proj   = (const float*)d_in[4];
    const float* b_proj   = (const float*)d_in[5];
    float* out = (float*)d_out;

    const size_t RW = 4096 * 512;            // words per [4096][1024-bf16] buffer
    uint32_t* qh = (uint32_t*)d_ws;          // 5 RW = 41.9 MB total (<= known-safe 50.3)
    uint32_t* ql = qh + RW;
    uint32_t* vb = ql + RW;
    uint32_t* xh = vb + RW;
    uint32_t* xl = xh + RW;
    uint32_t* kh = (uint32_t*)d_out;         // split K parked in d_out (16.8 MB);
    uint32_t* kl = kh + RW;                  // proj GEMM rewrites out afterwards

    dim3 blk(256);
    // split inputs once: aq -> xh/xl (dead after qv-GEMM, reused by flash out),
    //                    ak -> qh/ql (dead after k-GEMM, reused by qv-GEMM out)
    convert_in<<<dim3(4096), blk, 0, stream>>>(input_qv, input_k, xh, xl, qh, ql);
    // k projection: A=ak(qh/ql), B=W_k fp32, 128x64 tiles -> 512 blocks
    gemm_bt<64, 2><<<dim3(16, 32), blk, 0, stream>>>(
        qh, ql, W_k, nullptr, nullptr, kh, kl, nullptr, 1024);
    // qv projection: A=aq(xh/xl), B=W_qv fp32, 128x128 tiles -> 512 blocks
    gemm_bt<128, 1><<<dim3(16, 32), blk, 0, stream>>>(
        xh, xl, W_qv, nullptr, nullptr, qh, ql, vb, 2048);
    // flash attention
    flash_attn<<<dim3(SEQ / 128, NH, BATCH), blk, 0, stream>>>(
        qh, ql, kh, kl, vb, xh, xl);
    // output projection + bias: A=x(xh/xl), B=W_proj fp32, 128x64 -> 512 blocks
    gemm_bt<64, 0><<<dim3(16, 32), blk, 0, stream>>>(
        xh, xl, W_proj, b_proj, out, nullptr, nullptr, nullptr, 1024);
}